// Round 3
// baseline (288.204 us; speedup 1.0000x reference)
//
#include <hip/hip_runtime.h>

#define BB 4
#define NN 2048
#define DD 256
#define TILE_N 32                 // n per block
#define NPW 8                     // n per wave (4 waves * 8 = 32)
#define NT (NN / TILE_N)          // 64 n-tiles
#define MSPLIT 2                  // m-range halves -> grid 16*64*2 = 2048 blocks
#define MLEN (NN / MSPLIT)        // 1024 m per block
#define MCH (MLEN / 64)           // 16 chunks
#define WQ_CAP 96                 // per-wave hit queue (lambda ~5.4, Poisson tail safe)

// Kernel 1: rnorm[row] = 1/||features[row,:]||. One wave per row.
// Also zero-inits global accumulators (ws is poisoned 0xAA).
__global__ __launch_bounds__(256) void rnorm_kernel(const float* __restrict__ feat,
                                                    float* __restrict__ rnorm,
                                                    float* gsum, unsigned int* gcnt) {
    if (blockIdx.x == 0 && threadIdx.x < 2) {
        if (threadIdx.x == 0) *gsum = 0.0f;
        else                  *gcnt = 0u;
    }
    const int wave = threadIdx.x >> 6;
    const int lane = threadIdx.x & 63;
    const int row  = blockIdx.x * 4 + wave;              // 0..8191
    const float4 v = ((const float4*)(feat + (size_t)row * DD))[lane];
    float s = fmaf(v.x, v.x, fmaf(v.y, v.y, fmaf(v.z, v.z, v.w * v.w)));
#pragma unroll
    for (int off = 32; off >= 1; off >>= 1) s += __shfl_xor(s, off, 64);
    if (lane == 0) {
        float rn = rsqrtf(s);
        rn = rn * (1.5f - 0.5f * s * rn * rn);           // one Newton step
        rnorm[row] = rn;
    }
}

// Kernel 2: block = (pair, n-tile of 32, m-half of 1024). Loop structure:
// outer over m-chunks (1 ds_read each), inner over 8 n from registers.
// Rare hits -> per-wave LDS queue; tail processes 16 hits in parallel
// (4 lanes per hit, deep vmcnt pipelining, no per-hit shuffle chains).
__global__ __launch_bounds__(256) void scan_kernel(const float* __restrict__ feat,
                                                   const float* __restrict__ pts_src,
                                                   const float* __restrict__ pts_dst,
                                                   const float* __restrict__ rnorm,
                                                   const int* __restrict__ hptr,
                                                   const int* __restrict__ wptr,
                                                   float* gsum, unsigned int* gcnt) {
    __shared__ float2 spd[MLEN];                         // denormed dst points (8 KB)
    __shared__ unsigned int wq[4][WQ_CAP];               // per-wave hit queues
    __shared__ unsigned int wqc[4];
    const int pair  = blockIdx.x >> 7;                   // / (NT*MSPLIT)
    const int tile  = (blockIdx.x >> 1) & (NT - 1);
    const int mhalf = blockIdx.x & 1;
    const int mbase = mhalf * MLEN;
    const int i = pair >> 2;
    const int j = pair & 3;
    const float sx = ((float)(*wptr) - 1.0f) * 0.5f;
    const float sy = ((float)(*hptr) - 1.0f) * 0.5f;

    const int wave = threadIdx.x >> 6;
    const int lane = threadIdx.x & 63;

    {   // cooperative staging of this block's m-half: 1024 float2 = 512 float4
        const float4* src = (const float4*)(pts_dst) + (size_t)pair * (NN / 2) + mhalf * (MLEN / 2);
        float4* dst = (float4*)spd;
#pragma unroll
        for (int t = 0; t < 2; ++t) {
            const int idx = t * 256 + threadIdx.x;
            float4 v = src[idx];
            v.x = (v.x + 1.0f) * sx;  v.y = (v.y + 1.0f) * sy;
            v.z = (v.z + 1.0f) * sx;  v.w = (v.w + 1.0f) * sy;
            dst[idx] = v;
        }
    }
    if (lane == 0) wqc[wave] = 0u;
    __syncthreads();

    const int nbase = tile * TILE_N + wave * NPW;
    float psx[NPW], psy[NPW];
#pragma unroll
    for (int k = 0; k < NPW; ++k) {
        psx[k] = (pts_src[(size_t)(i * NN + nbase + k) * 2 + 0] + 1.0f) * sx;
        psy[k] = (pts_src[(size_t)(i * NN + nbase + k) * 2 + 1] + 1.0f) * sy;
    }

    // ---- scan: 16 chunks, points from LDS once, 8 n from registers ----
    for (int c = 0; c < MCH; ++c) {
        const float2 q = spd[c * 64 + lane];
        float d2v[NPW];
#pragma unroll
        for (int k = 0; k < NPW; ++k) {
            const float dx = psx[k] - q.x;
            const float dy = psy[k] - q.y;
            d2v[k] = fmaf(dx, dx, dy * dy);
        }
        const float mn = fminf(fminf(fminf(d2v[0], d2v[1]), fminf(d2v[2], d2v[3])),
                               fminf(fminf(d2v[4], d2v[5]), fminf(d2v[6], d2v[7])));
        if (__ballot(mn <= 64.0f)) {                     // ~28% of chunks
            const unsigned int m = (unsigned int)(mbase + c * 64 + lane);
#pragma unroll
            for (int k = 0; k < NPW; ++k) {
                if (d2v[k] <= 64.0f) {
                    const unsigned int slot = atomicAdd(&wqc[wave], 1u);
                    if (slot < WQ_CAP) wq[wave][slot] = ((unsigned int)k << 11) | m;
                }
            }
        }
    }

    // ---- tail: process this wave's hits, 16 at a time (4 lanes per hit) ----
    const unsigned int hc = min(wqc[wave], (unsigned int)WQ_CAP);
    const int g = lane >> 2, sub = lane & 3;
    float lsum = 0.0f;
    for (unsigned int h0 = 0; h0 < hc; h0 += 16) {
        const unsigned int hid = h0 + (unsigned int)g;
        const bool valid = hid < hc;
        float part = 0.0f;
        int n = 0, m = 0;
        if (valid) {
            const unsigned int rec = wq[wave][hid];
            m = (int)(rec & 2047u);
            n = nbase + (int)(rec >> 11);
            const float4* pa = (const float4*)(feat + (size_t)(j * NN + n) * DD);
            const float4* pb = (const float4*)(feat + (size_t)(i * NN + m) * DD);
#pragma unroll
            for (int t = 0; t < 16; ++t) {
                const float4 a = pa[t * 4 + sub];
                const float4 b = pb[t * 4 + sub];
                part = fmaf(a.x, b.x, fmaf(a.y, b.y, fmaf(a.z, b.z, fmaf(a.w, b.w, part))));
            }
        }
        part += __shfl_xor(part, 1, 64);                 // reduce across the 4 lanes
        part += __shfl_xor(part, 2, 64);
        if (valid && sub == 0)
            lsum += 1.0f - part * rnorm[j * NN + n] * rnorm[i * NN + m];
    }
#pragma unroll
    for (int off = 32; off >= 1; off >>= 1) lsum += __shfl_xor(lsum, off, 64);
    if (lane == 0) {
        atomicAdd(gsum, lsum);
        atomicAdd(gcnt, hc);
    }
}

__global__ void finalize_kernel(const float* gsum, const unsigned int* gcnt,
                                float* out) {
    if (threadIdx.x == 0 && blockIdx.x == 0) {
        const unsigned int c = *gcnt;
        const float denom = (c > 0u) ? (float)c : 1.0f;  // max(cnt, 1)
        out[0] = *gsum / denom;
    }
}

extern "C" void kernel_launch(void* const* d_in, const int* in_sizes, int n_in,
                              void* d_out, int out_size, void* d_ws, size_t ws_size,
                              hipStream_t stream) {
    const float* feat    = (const float*)d_in[0];   // [B,N,D] f32
    const float* pts_src = (const float*)d_in[1];   // [B,N,2] f32
    const float* pts_dst = (const float*)d_in[2];   // [B,B,N,2] f32
    // d_in[3] = invis_idx — unused by the reference
    const int* hptr = (const int*)d_in[4];          // height (scalar)
    const int* wptr = (const int*)d_in[5];          // width  (scalar)
    float* out = (float*)d_out;

    float*        gsum  = (float*)d_ws;
    unsigned int* gcnt  = (unsigned int*)((char*)d_ws + 4);
    float*        rnorm = (float*)((char*)d_ws + 16);    // 8192 floats

    rnorm_kernel<<<BB * NN / 4, 256, 0, stream>>>(feat, rnorm, gsum, gcnt);
    scan_kernel<<<BB * BB * NT * MSPLIT, 256, 0, stream>>>(feat, pts_src, pts_dst,
                                                           rnorm, hptr, wptr, gsum, gcnt);
    finalize_kernel<<<1, 64, 0, stream>>>(gsum, gcnt, out);
}

// Round 4
// 89.561 us; speedup vs baseline: 3.2180x; 3.2180x over previous
//
#include <hip/hip_runtime.h>

#define BB 4
#define NN 2048
#define DD 256
#define TILE_N 32                 // n per block
#define NPW 8                     // n per wave (4 waves * 8 = 32)
#define NT (NN / TILE_N)          // 64 n-tiles
#define MSPLIT 2                  // m-range halves
#define MLEN (NN / MSPLIT)        // 1024 m per block
#define MCH (MLEN / 64)           // 16 chunks
#define WQ_CAP 96                 // per-wave hit queue (lambda ~5.4)
#define NBLK (BB * BB * NT * MSPLIT)   // 2048 scan blocks

// Kernel 1: rnorm[row] = 1/||features[row,:]||. One wave per row.
__global__ __launch_bounds__(256) void rnorm_kernel(const float* __restrict__ feat,
                                                    float* __restrict__ rnorm) {
    const int wave = threadIdx.x >> 6;
    const int lane = threadIdx.x & 63;
    const int row  = blockIdx.x * 4 + wave;              // 0..8191
    const float4 v = ((const float4*)(feat + (size_t)row * DD))[lane];
    float s = fmaf(v.x, v.x, fmaf(v.y, v.y, fmaf(v.z, v.z, v.w * v.w)));
#pragma unroll
    for (int off = 32; off >= 1; off >>= 1) s += __shfl_xor(s, off, 64);
    if (lane == 0) {
        float rn = rsqrtf(s);
        rn = rn * (1.5f - 0.5f * s * rn * rn);           // one Newton step
        rnorm[row] = rn;
    }
}

// Kernel 2: block = (pair, n-tile of 32, m-half of 1024).
// NO global atomics: each block writes its partial (sum,cnt) to a private
// slot; finalize_kernel reduces. (Rounds 1-3 were dominated by same-address
// atomic serialization: ~12.5 ns/op * 16384 ops = 205 us.)
__global__ __launch_bounds__(256) void scan_kernel(const float* __restrict__ feat,
                                                   const float* __restrict__ pts_src,
                                                   const float* __restrict__ pts_dst,
                                                   const float* __restrict__ rnorm,
                                                   const int* __restrict__ hptr,
                                                   const int* __restrict__ wptr,
                                                   float* __restrict__ psum,
                                                   unsigned int* __restrict__ pcnt) {
    __shared__ float2 spd[MLEN];                         // denormed dst points (8 KB)
    __shared__ unsigned int wq[4][WQ_CAP];               // per-wave hit queues
    __shared__ unsigned int wqc[4];
    __shared__ float bsum[4];
    __shared__ unsigned int bcnt[4];
    const int pair  = blockIdx.x >> 7;                   // / (NT*MSPLIT)
    const int tile  = (blockIdx.x >> 1) & (NT - 1);
    const int mhalf = blockIdx.x & 1;
    const int mbase = mhalf * MLEN;
    const int i = pair >> 2;
    const int j = pair & 3;
    const float sx = ((float)(*wptr) - 1.0f) * 0.5f;
    const float sy = ((float)(*hptr) - 1.0f) * 0.5f;

    const int wave = threadIdx.x >> 6;
    const int lane = threadIdx.x & 63;

    {   // cooperative staging of this block's m-half: 1024 float2 = 512 float4
        const float4* src = (const float4*)(pts_dst) + (size_t)pair * (NN / 2) + mhalf * (MLEN / 2);
        float4* dst = (float4*)spd;
#pragma unroll
        for (int t = 0; t < 2; ++t) {
            const int idx = t * 256 + threadIdx.x;
            float4 v = src[idx];
            v.x = (v.x + 1.0f) * sx;  v.y = (v.y + 1.0f) * sy;
            v.z = (v.z + 1.0f) * sx;  v.w = (v.w + 1.0f) * sy;
            dst[idx] = v;
        }
    }
    if (lane == 0) wqc[wave] = 0u;
    __syncthreads();

    const int nbase = tile * TILE_N + wave * NPW;
    float psx[NPW], psy[NPW];
#pragma unroll
    for (int k = 0; k < NPW; ++k) {
        psx[k] = (pts_src[(size_t)(i * NN + nbase + k) * 2 + 0] + 1.0f) * sx;
        psy[k] = (pts_src[(size_t)(i * NN + nbase + k) * 2 + 1] + 1.0f) * sy;
    }

    // ---- scan: 16 chunks, points from LDS once, 8 n from registers ----
    for (int c = 0; c < MCH; ++c) {
        const float2 q = spd[c * 64 + lane];
        float d2v[NPW];
#pragma unroll
        for (int k = 0; k < NPW; ++k) {
            const float dx = psx[k] - q.x;
            const float dy = psy[k] - q.y;
            d2v[k] = fmaf(dx, dx, dy * dy);
        }
        const float mn = fminf(fminf(fminf(d2v[0], d2v[1]), fminf(d2v[2], d2v[3])),
                               fminf(fminf(d2v[4], d2v[5]), fminf(d2v[6], d2v[7])));
        if (__ballot(mn <= 64.0f)) {                     // ~28% of chunks
            const unsigned int m = (unsigned int)(mbase + c * 64 + lane);
#pragma unroll
            for (int k = 0; k < NPW; ++k) {
                if (d2v[k] <= 64.0f) {
                    const unsigned int slot = atomicAdd(&wqc[wave], 1u);  // LDS, per-wave
                    if (slot < WQ_CAP) wq[wave][slot] = ((unsigned int)k << 11) | m;
                }
            }
        }
    }

    // ---- tail: process this wave's hits, 16 at a time (4 lanes per hit) ----
    const unsigned int hc = min(wqc[wave], (unsigned int)WQ_CAP);
    const int g = lane >> 2, sub = lane & 3;
    float lsum = 0.0f;
    for (unsigned int h0 = 0; h0 < hc; h0 += 16) {
        const unsigned int hid = h0 + (unsigned int)g;
        const bool valid = hid < hc;
        float part = 0.0f;
        int n = 0, m = 0;
        if (valid) {
            const unsigned int rec = wq[wave][hid];
            m = (int)(rec & 2047u);
            n = nbase + (int)(rec >> 11);
            const float4* pa = (const float4*)(feat + (size_t)(j * NN + n) * DD);
            const float4* pb = (const float4*)(feat + (size_t)(i * NN + m) * DD);
#pragma unroll
            for (int t = 0; t < 16; ++t) {
                const float4 a = pa[t * 4 + sub];
                const float4 b = pb[t * 4 + sub];
                part = fmaf(a.x, b.x, fmaf(a.y, b.y, fmaf(a.z, b.z, fmaf(a.w, b.w, part))));
            }
        }
        part += __shfl_xor(part, 1, 64);                 // reduce across the 4 lanes
        part += __shfl_xor(part, 2, 64);
        if (valid && sub == 0)
            lsum += 1.0f - part * rnorm[j * NN + n] * rnorm[i * NN + m];
    }
#pragma unroll
    for (int off = 32; off >= 1; off >>= 1) lsum += __shfl_xor(lsum, off, 64);

    // ---- block reduction -> private slot (plain stores, no atomics) ----
    if (lane == 0) { bsum[wave] = lsum; bcnt[wave] = hc; }
    __syncthreads();
    if (threadIdx.x == 0) {
        psum[blockIdx.x] = bsum[0] + bsum[1] + bsum[2] + bsum[3];
        pcnt[blockIdx.x] = bcnt[0] + bcnt[1] + bcnt[2] + bcnt[3];
    }
}

// Kernel 3: reduce the 2048 block partials. One block.
__global__ __launch_bounds__(256) void finalize_kernel(const float* __restrict__ psum,
                                                       const unsigned int* __restrict__ pcnt,
                                                       float* __restrict__ out) {
    float s = 0.0f;
    float c = 0.0f;                                      // hits < 2^24, exact in f32
    for (int t = threadIdx.x; t < NBLK; t += 256) {
        s += psum[t];
        c += (float)pcnt[t];
    }
#pragma unroll
    for (int off = 32; off >= 1; off >>= 1) {
        s += __shfl_xor(s, off, 64);
        c += __shfl_xor(c, off, 64);
    }
    __shared__ float ss[4], cc[4];
    const int wave = threadIdx.x >> 6;
    const int lane = threadIdx.x & 63;
    if (lane == 0) { ss[wave] = s; cc[wave] = c; }
    __syncthreads();
    if (threadIdx.x == 0) {
        const float S = ss[0] + ss[1] + ss[2] + ss[3];
        const float C = cc[0] + cc[1] + cc[2] + cc[3];
        out[0] = S / fmaxf(C, 1.0f);                     // max(cnt, 1)
    }
}

extern "C" void kernel_launch(void* const* d_in, const int* in_sizes, int n_in,
                              void* d_out, int out_size, void* d_ws, size_t ws_size,
                              hipStream_t stream) {
    const float* feat    = (const float*)d_in[0];   // [B,N,D] f32
    const float* pts_src = (const float*)d_in[1];   // [B,N,2] f32
    const float* pts_dst = (const float*)d_in[2];   // [B,B,N,2] f32
    // d_in[3] = invis_idx — unused by the reference
    const int* hptr = (const int*)d_in[4];          // height (scalar)
    const int* wptr = (const int*)d_in[5];          // width  (scalar)
    float* out = (float*)d_out;

    float*        psum  = (float*)d_ws;                          // 8 KB
    unsigned int* pcnt  = (unsigned int*)((char*)d_ws + 8192);   // 8 KB
    float*        rnorm = (float*)((char*)d_ws + 16384);         // 32 KB

    rnorm_kernel<<<BB * NN / 4, 256, 0, stream>>>(feat, rnorm);
    scan_kernel<<<NBLK, 256, 0, stream>>>(feat, pts_src, pts_dst,
                                          rnorm, hptr, wptr, psum, pcnt);
    finalize_kernel<<<1, 256, 0, stream>>>(psum, pcnt, out);
}

// Round 5
// 87.586 us; speedup vs baseline: 3.2905x; 1.0226x over previous
//
#include <hip/hip_runtime.h>

#define BB 4
#define NN 2048
#define DD 256
#define TILE_N 32                 // n per block
#define NPW 8                     // n per wave (4 waves * 8 = 32)
#define NT (NN / TILE_N)          // 64 n-tiles
#define MSPLIT 2                  // m-range halves
#define MLEN (NN / MSPLIT)        // 1024 m per block
#define MCH (MLEN / 128)          // 8 chunks of 128 m (ds_read_b128: 2 pts/lane)
#define WQ_CAP 96                 // per-wave hit queue (lambda ~5.4)
#define NBLK (BB * BB * NT * MSPLIT)   // 2048 scan blocks

// Kernel 1: block = (pair, n-tile of 32, m-half of 1024).
// Scan: 8 chunks x 128 m, one ds_read_b128 per chunk (2 points/lane), 8 n
// from registers. Sparse hits -> per-wave LDS queue. Tail: 16 hits in
// parallel (4 lanes/hit), computing dot AND both row norms in one stream
// (rnorm kernel eliminated). No global atomics: partials to private slots.
__global__ __launch_bounds__(256) void scan_kernel(const float* __restrict__ feat,
                                                   const float* __restrict__ pts_src,
                                                   const float* __restrict__ pts_dst,
                                                   const int* __restrict__ hptr,
                                                   const int* __restrict__ wptr,
                                                   float* __restrict__ psum,
                                                   unsigned int* __restrict__ pcnt) {
    __shared__ float4 spd[MLEN / 2];                     // denormed dst pts (8 KB)
    __shared__ unsigned int wq[4][WQ_CAP];               // per-wave hit queues
    __shared__ unsigned int wqc[4];
    __shared__ float bsum[4];
    __shared__ unsigned int bcnt[4];
    const int pair  = blockIdx.x >> 7;                   // / (NT*MSPLIT)
    const int tile  = (blockIdx.x >> 1) & (NT - 1);
    const int mhalf = blockIdx.x & 1;
    const int mbase = mhalf * MLEN;
    const int i = pair >> 2;
    const int j = pair & 3;
    const float sx = ((float)(*wptr) - 1.0f) * 0.5f;
    const float sy = ((float)(*hptr) - 1.0f) * 0.5f;

    const int wave = threadIdx.x >> 6;
    const int lane = threadIdx.x & 63;

    {   // cooperative staging of this block's m-half: 512 float4
        const float4* src = (const float4*)(pts_dst) + (size_t)pair * (NN / 2) + mhalf * (MLEN / 2);
#pragma unroll
        for (int t = 0; t < 2; ++t) {
            const int idx = t * 256 + threadIdx.x;
            float4 v = src[idx];
            v.x = (v.x + 1.0f) * sx;  v.y = (v.y + 1.0f) * sy;
            v.z = (v.z + 1.0f) * sx;  v.w = (v.w + 1.0f) * sy;
            spd[idx] = v;
        }
    }
    if (lane == 0) wqc[wave] = 0u;
    __syncthreads();

    const int nbase = tile * TILE_N + wave * NPW;
    float psx[NPW], psy[NPW];
#pragma unroll
    for (int k = 0; k < NPW; ++k) {
        psx[k] = (pts_src[(size_t)(i * NN + nbase + k) * 2 + 0] + 1.0f) * sx;
        psy[k] = (pts_src[(size_t)(i * NN + nbase + k) * 2 + 1] + 1.0f) * sy;
    }

    // ---- scan: 8 chunks of 128 m; 2 points/lane from one ds_read_b128 ----
    for (int c = 0; c < MCH; ++c) {
        const float4 q = spd[c * 64 + lane];             // pts 2*lane, 2*lane+1
        float d0[NPW], d1[NPW];
#pragma unroll
        for (int k = 0; k < NPW; ++k) {
            const float ax = psx[k] - q.x, ay = psy[k] - q.y;
            const float bx = psx[k] - q.z, by = psy[k] - q.w;
            d0[k] = fmaf(ax, ax, ay * ay);
            d1[k] = fmaf(bx, bx, by * by);
        }
        float mn = fminf(d0[0], d1[0]);
#pragma unroll
        for (int k = 1; k < NPW; ++k) mn = fminf(mn, fminf(d0[k], d1[k]));
        if (__ballot(mn <= 64.0f)) {                     // rare slow path
            const unsigned int m2 = (unsigned int)(mbase + c * 128 + 2 * lane);
#pragma unroll
            for (int k = 0; k < NPW; ++k) {
                if (d0[k] <= 64.0f) {
                    const unsigned int slot = atomicAdd(&wqc[wave], 1u);  // LDS
                    if (slot < WQ_CAP) wq[wave][slot] = ((unsigned int)k << 11) | m2;
                }
                if (d1[k] <= 64.0f) {
                    const unsigned int slot = atomicAdd(&wqc[wave], 1u);  // LDS
                    if (slot < WQ_CAP) wq[wave][slot] = ((unsigned int)k << 11) | (m2 + 1u);
                }
            }
        }
    }

    // ---- tail: 16 hits at a time, 4 lanes/hit; dot + both norms fused ----
    const unsigned int hc = min(wqc[wave], (unsigned int)WQ_CAP);
    const int g = lane >> 2, sub = lane & 3;
    float lsum = 0.0f;
    for (unsigned int h0 = 0; h0 < hc; h0 += 16) {
        const unsigned int hid = h0 + (unsigned int)g;
        const bool valid = hid < hc;
        float dd = 0.0f, aa = 0.0f, bb = 0.0f;
        if (valid) {
            const unsigned int rec = wq[wave][hid];
            const int m = (int)(rec & 2047u);
            const int n = nbase + (int)(rec >> 11);
            const float4* pa = (const float4*)(feat + (size_t)(j * NN + n) * DD);
            const float4* pb = (const float4*)(feat + (size_t)(i * NN + m) * DD);
#pragma unroll
            for (int t = 0; t < 16; ++t) {
                const float4 a = pa[t * 4 + sub];
                const float4 b = pb[t * 4 + sub];
                dd = fmaf(a.x, b.x, fmaf(a.y, b.y, fmaf(a.z, b.z, fmaf(a.w, b.w, dd))));
                aa = fmaf(a.x, a.x, fmaf(a.y, a.y, fmaf(a.z, a.z, fmaf(a.w, a.w, aa))));
                bb = fmaf(b.x, b.x, fmaf(b.y, b.y, fmaf(b.z, b.z, fmaf(b.w, b.w, bb))));
            }
        }
        dd += __shfl_xor(dd, 1, 64);  aa += __shfl_xor(aa, 1, 64);  bb += __shfl_xor(bb, 1, 64);
        dd += __shfl_xor(dd, 2, 64);  aa += __shfl_xor(aa, 2, 64);  bb += __shfl_xor(bb, 2, 64);
        if (valid && sub == 0) {
            const float p = aa * bb;                     // (|fa|*|fb|)^2, ~256 >> eps^2
            float r = rsqrtf(p);
            r = r * (1.5f - 0.5f * p * r * r);           // one Newton step
            lsum += 1.0f - dd * r;
        }
    }
#pragma unroll
    for (int off = 32; off >= 1; off >>= 1) lsum += __shfl_xor(lsum, off, 64);

    // ---- block reduction -> private slot (plain stores, no atomics) ----
    if (lane == 0) { bsum[wave] = lsum; bcnt[wave] = hc; }
    __syncthreads();
    if (threadIdx.x == 0) {
        psum[blockIdx.x] = bsum[0] + bsum[1] + bsum[2] + bsum[3];
        pcnt[blockIdx.x] = bcnt[0] + bcnt[1] + bcnt[2] + bcnt[3];
    }
}

// Kernel 2: reduce the 2048 block partials. One block.
__global__ __launch_bounds__(256) void finalize_kernel(const float* __restrict__ psum,
                                                       const unsigned int* __restrict__ pcnt,
                                                       float* __restrict__ out) {
    float s = 0.0f;
    float c = 0.0f;                                      // hits < 2^24, exact in f32
    for (int t = threadIdx.x; t < NBLK; t += 256) {
        s += psum[t];
        c += (float)pcnt[t];
    }
#pragma unroll
    for (int off = 32; off >= 1; off >>= 1) {
        s += __shfl_xor(s, off, 64);
        c += __shfl_xor(c, off, 64);
    }
    __shared__ float ss[4], cc[4];
    const int wave = threadIdx.x >> 6;
    const int lane = threadIdx.x & 63;
    if (lane == 0) { ss[wave] = s; cc[wave] = c; }
    __syncthreads();
    if (threadIdx.x == 0) {
        const float S = ss[0] + ss[1] + ss[2] + ss[3];
        const float C = cc[0] + cc[1] + cc[2] + cc[3];
        out[0] = S / fmaxf(C, 1.0f);                     // max(cnt, 1)
    }
}

extern "C" void kernel_launch(void* const* d_in, const int* in_sizes, int n_in,
                              void* d_out, int out_size, void* d_ws, size_t ws_size,
                              hipStream_t stream) {
    const float* feat    = (const float*)d_in[0];   // [B,N,D] f32
    const float* pts_src = (const float*)d_in[1];   // [B,N,2] f32
    const float* pts_dst = (const float*)d_in[2];   // [B,B,N,2] f32
    // d_in[3] = invis_idx — unused by the reference
    const int* hptr = (const int*)d_in[4];          // height (scalar)
    const int* wptr = (const int*)d_in[5];          // width  (scalar)
    float* out = (float*)d_out;

    float*        psum  = (float*)d_ws;                          // 8 KB
    unsigned int* pcnt  = (unsigned int*)((char*)d_ws + 8192);   // 8 KB

    scan_kernel<<<NBLK, 256, 0, stream>>>(feat, pts_src, pts_dst,
                                          hptr, wptr, psum, pcnt);
    finalize_kernel<<<1, 256, 0, stream>>>(psum, pcnt, out);
}

// Round 6
// 86.192 us; speedup vs baseline: 3.3438x; 1.0162x over previous
//
#include <hip/hip_runtime.h>

#define BB 4
#define NN 2048
#define DD 256
#define TILE_N 32                 // n per block
#define NPW 8                     // n per wave (4 waves * 8 = 32)
#define NT (NN / TILE_N)          // 64 n-tiles
#define MSPLIT 2                  // m-range halves
#define MLEN (NN / MSPLIT)        // 1024 m per block
#define MCH (MLEN / 128)          // 8 chunks of 128 m (2 points/lane)
#define WQ_CAP 96                 // per-wave hit queue (lambda ~5.4)
#define NBLK (BB * BB * NT * MSPLIT)   // 2048 blocks = 8/CU, all co-resident

// Kernel 1: block = (pair, n-tile of 32, m-half of 1024).
// NO LDS staging, NO __syncthreads before the scan: each lane reads its
// chunk's points directly from global (L2-resident, prefetched 1 chunk
// ahead, denorm on the fly). Per-wave chain ~3K cycles; full grid
// co-resident. Hits -> per-wave LDS queue; tail: 16 hits in parallel
// (4 lanes/hit) with dot + both norms fused. Partials to private slots.
__global__ __launch_bounds__(256) void scan_kernel(const float* __restrict__ feat,
                                                   const float* __restrict__ pts_src,
                                                   const float* __restrict__ pts_dst,
                                                   const int* __restrict__ hptr,
                                                   const int* __restrict__ wptr,
                                                   float* __restrict__ psum,
                                                   unsigned int* __restrict__ pcnt) {
    __shared__ unsigned int wq[4][WQ_CAP];               // per-wave hit queues
    __shared__ unsigned int wqc[4];
    __shared__ float bsum[4];
    __shared__ unsigned int bcnt[4];
    const int pair  = blockIdx.x >> 7;                   // / (NT*MSPLIT)
    const int tile  = (blockIdx.x >> 1) & (NT - 1);
    const int mhalf = blockIdx.x & 1;
    const int mbase = mhalf * MLEN;
    const int i = pair >> 2;
    const int j = pair & 3;
    const float sx = ((float)(*wptr) - 1.0f) * 0.5f;
    const float sy = ((float)(*hptr) - 1.0f) * 0.5f;

    const int wave = threadIdx.x >> 6;
    const int lane = threadIdx.x & 63;
    if (lane == 0) wqc[wave] = 0u;                       // same-wave order: no barrier

    const int nbase = tile * TILE_N + wave * NPW;
    float psx[NPW], psy[NPW];
#pragma unroll
    for (int k = 0; k < NPW; ++k) {
        psx[k] = fmaf(pts_src[(size_t)(i * NN + nbase + k) * 2 + 0], sx, sx);
        psy[k] = fmaf(pts_src[(size_t)(i * NN + nbase + k) * 2 + 1], sy, sy);
    }

    // lane's view of this block's m-half: float4 = 2 raw points
    const float4* pd = (const float4*)(pts_dst + (size_t)pair * NN * 2 + (size_t)mbase * 2);

    float4 q = pd[lane];                                 // prefetch chunk 0
#pragma unroll
    for (int c = 0; c < MCH; ++c) {
        float4 qn;
        if (c + 1 < MCH) qn = pd[(c + 1) * 64 + lane];   // prefetch next
        const float qx0 = fmaf(q.x, sx, sx), qy0 = fmaf(q.y, sy, sy);
        const float qx1 = fmaf(q.z, sx, sx), qy1 = fmaf(q.w, sy, sy);
        float mn = 1e30f;
#pragma unroll
        for (int k = 0; k < NPW; ++k) {                  // d0/d1 transient (low VGPR)
            const float ax = psx[k] - qx0, ay = psy[k] - qy0;
            const float bx = psx[k] - qx1, by = psy[k] - qy1;
            mn = fminf(mn, fminf(fmaf(ax, ax, ay * ay), fmaf(bx, bx, by * by)));
        }
        if (__ballot(mn <= 64.0f)) {                     // rare slow path: recompute
            const unsigned int m2 = (unsigned int)(mbase + c * 128 + 2 * lane);
#pragma unroll
            for (int k = 0; k < NPW; ++k) {
                const float ax = psx[k] - qx0, ay = psy[k] - qy0;
                const float bx = psx[k] - qx1, by = psy[k] - qy1;
                const float d0 = fmaf(ax, ax, ay * ay);
                const float d1 = fmaf(bx, bx, by * by);
                if (fminf(d0, d1) <= 64.0f) {            // per-k early-out
                    if (d0 <= 64.0f) {
                        const unsigned int slot = atomicAdd(&wqc[wave], 1u);
                        if (slot < WQ_CAP) wq[wave][slot] = ((unsigned int)k << 11) | m2;
                    }
                    if (d1 <= 64.0f) {
                        const unsigned int slot = atomicAdd(&wqc[wave], 1u);
                        if (slot < WQ_CAP) wq[wave][slot] = ((unsigned int)k << 11) | (m2 + 1u);
                    }
                }
            }
        }
        q = qn;
    }

    // ---- tail: 16 hits at a time, 4 lanes/hit; dot + both norms fused ----
    const unsigned int hc = min(wqc[wave], (unsigned int)WQ_CAP);
    const int g = lane >> 2, sub = lane & 3;
    float lsum = 0.0f;
    for (unsigned int h0 = 0; h0 < hc; h0 += 16) {
        const unsigned int hid = h0 + (unsigned int)g;
        const bool valid = hid < hc;
        float dd = 0.0f, aa = 0.0f, bb = 0.0f;
        if (valid) {
            const unsigned int rec = wq[wave][hid];
            const int m = (int)(rec & 2047u);
            const int n = nbase + (int)(rec >> 11);
            const float4* pa = (const float4*)(feat + (size_t)(j * NN + n) * DD);
            const float4* pb = (const float4*)(feat + (size_t)(i * NN + m) * DD);
#pragma unroll
            for (int t = 0; t < 16; ++t) {
                const float4 a = pa[t * 4 + sub];
                const float4 b = pb[t * 4 + sub];
                dd = fmaf(a.x, b.x, fmaf(a.y, b.y, fmaf(a.z, b.z, fmaf(a.w, b.w, dd))));
                aa = fmaf(a.x, a.x, fmaf(a.y, a.y, fmaf(a.z, a.z, fmaf(a.w, a.w, aa))));
                bb = fmaf(b.x, b.x, fmaf(b.y, b.y, fmaf(b.z, b.z, fmaf(b.w, b.w, bb))));
            }
        }
        dd += __shfl_xor(dd, 1, 64);  aa += __shfl_xor(aa, 1, 64);  bb += __shfl_xor(bb, 1, 64);
        dd += __shfl_xor(dd, 2, 64);  aa += __shfl_xor(aa, 2, 64);  bb += __shfl_xor(bb, 2, 64);
        if (valid && sub == 0) {
            const float p = aa * bb;                     // (|fa|*|fb|)^2 >> eps^2
            float r = rsqrtf(p);
            r = r * (1.5f - 0.5f * p * r * r);           // one Newton step
            lsum += 1.0f - dd * r;
        }
    }
#pragma unroll
    for (int off = 32; off >= 1; off >>= 1) lsum += __shfl_xor(lsum, off, 64);

    // ---- block reduction -> private slot (plain stores, no atomics) ----
    if (lane == 0) { bsum[wave] = lsum; bcnt[wave] = hc; }
    __syncthreads();
    if (threadIdx.x == 0) {
        psum[blockIdx.x] = bsum[0] + bsum[1] + bsum[2] + bsum[3];
        pcnt[blockIdx.x] = bcnt[0] + bcnt[1] + bcnt[2] + bcnt[3];
    }
}

// Kernel 2: reduce the 2048 block partials. One block.
__global__ __launch_bounds__(256) void finalize_kernel(const float* __restrict__ psum,
                                                       const unsigned int* __restrict__ pcnt,
                                                       float* __restrict__ out) {
    float s = 0.0f;
    float c = 0.0f;                                      // hits < 2^24, exact in f32
    for (int t = threadIdx.x; t < NBLK; t += 256) {
        s += psum[t];
        c += (float)pcnt[t];
    }
#pragma unroll
    for (int off = 32; off >= 1; off >>= 1) {
        s += __shfl_xor(s, off, 64);
        c += __shfl_xor(c, off, 64);
    }
    __shared__ float ss[4], cc[4];
    const int wave = threadIdx.x >> 6;
    const int lane = threadIdx.x & 63;
    if (lane == 0) { ss[wave] = s; cc[wave] = c; }
    __syncthreads();
    if (threadIdx.x == 0) {
        const float S = ss[0] + ss[1] + ss[2] + ss[3];
        const float C = cc[0] + cc[1] + cc[2] + cc[3];
        out[0] = S / fmaxf(C, 1.0f);                     // max(cnt, 1)
    }
}

extern "C" void kernel_launch(void* const* d_in, const int* in_sizes, int n_in,
                              void* d_out, int out_size, void* d_ws, size_t ws_size,
                              hipStream_t stream) {
    const float* feat    = (const float*)d_in[0];   // [B,N,D] f32
    const float* pts_src = (const float*)d_in[1];   // [B,N,2] f32
    const float* pts_dst = (const float*)d_in[2];   // [B,B,N,2] f32
    // d_in[3] = invis_idx — unused by the reference
    const int* hptr = (const int*)d_in[4];          // height (scalar)
    const int* wptr = (const int*)d_in[5];          // width  (scalar)
    float* out = (float*)d_out;

    float*        psum  = (float*)d_ws;                          // 8 KB
    unsigned int* pcnt  = (unsigned int*)((char*)d_ws + 8192);   // 8 KB

    scan_kernel<<<NBLK, 256, 0, stream>>>(feat, pts_src, pts_dst,
                                          hptr, wptr, psum, pcnt);
    finalize_kernel<<<1, 256, 0, stream>>>(psum, pcnt, out);
}